// Round 20
// baseline (2122.441 us; speedup 1.0000x reference)
//
#include <hip/hip_runtime.h>

using short8 = __attribute__((ext_vector_type(8))) short;
using f32x4  = __attribute__((ext_vector_type(4))) float;
using uint4v = __attribute__((ext_vector_type(4))) unsigned;

#define NT     512
#define NBATCH 64
#define NN     1024
#define NIN    24
#define NG     4                      // groups of 16 batches
#define ROWS   16
#define TILE32 (ROWS * NN)            // u32 per group tile
#define PARSTRIDE (NG * TILE32)       // u32 per parity buffer (256 KB)
#define SCOPE_AGENT __HIP_MEMORY_SCOPE_AGENT
#define RETRY_CAP (1 << 17)           // fail loud (absmax), never hang

// R19 = R15 (K-split: wave owns K-slice, A direct from global w/ tag
// validation, partials exchanged via conflict-free LDS — 0 bank conflicts,
// 128KB LDS/step vs R13's 544KB) + R18's clock pacing (s_memrealtime gate at
// T0 + t*P). R15 free-ran at 4.17us/step because its per-wave retry loops
// amplified skew; the gate makes first-try validation the steady state.
// Chain estimate: load .35 + MFMA .25 + exchange .3 + update .1 + vis .7
// ~= 1.8-2.1us -> P = 2.1us. Degrades to aligned free-run if P too small.

__device__ __forceinline__ unsigned short f2bf(float x) {
  union { float f; unsigned u; } v; v.f = x;
  return (unsigned short)((v.u + 0x7FFFu + ((v.u >> 16) & 1u)) >> 16);
}
__device__ __forceinline__ f32x4 MF(short8 a, short8 b, f32x4 c) {
  return __builtin_amdgcn_mfma_f32_16x16x32_bf16(a, b, c, 0, 0, 0);
}

#define PACKS8(dst, Rx, Ry) do { \
  union { unsigned u[4]; short8 s; } pk_; \
  pk_.u[0] = (Rx[0] & 0xFFFFu) | (Rx[1] << 16); \
  pk_.u[1] = (Rx[2] & 0xFFFFu) | (Rx[3] << 16); \
  pk_.u[2] = (Ry[0] & 0xFFFFu) | (Ry[1] << 16); \
  pk_.u[3] = (Ry[2] & 0xFFFFu) | (Ry[3] << 16); \
  dst = pk_.s; } while (0)

// 32 blocks x 512 thr (8 waves). Group g = bid&3 owns batches [16g,+16);
// slot = bid>>2 owns neurons [128*slot,+128). Wave w = K-slice [128w,+128)
// for the partial GEMM, and OWNS output col-set w (reduce + r-state + publish).
__global__ __launch_bounds__(512, 1) void rnn_step_all(
    const float* __restrict__ u, const float* __restrict__ r0,
    const float* __restrict__ W, const float* __restrict__ Bm,
    const float* __restrict__ tau, const float* __restrict__ ds,
    float* __restrict__ out, unsigned* __restrict__ obs32,
    unsigned long long P_ticks)
{
  __shared__ f32x4 pl[64][64];   // 64 KB: partial tile [c*8+w][lane], 16x16 f32

  const int tid  = threadIdx.x;
  const int wave = tid >> 6;
  const int lane = tid & 63;
  const int bid  = blockIdx.x;
  const int g    = bid & 3;
  const int slot = bid >> 2;
  const int b0   = g * ROWS;
  const int lr = lane & 15, lg = lane >> 4;
  const int i  = slot * 128 + wave * 16 + lr;   // OUTPUT neuron (col-set = wave)

  // ---- W fragments: ALL 8 col-sets x this wave's K-slice (128 VGPR) ----
  short8 wf[8][4];
#pragma unroll
  for (int c = 0; c < 8; ++c) {
#pragma unroll
    for (int j = 0; j < 4; ++j) {
      const int col = slot * 128 + c * 16 + lr;
      const int k0  = wave * 128 + j * 32 + lg * 8;
      f32x4 w0 = *(const f32x4*)(W + (size_t)col * NN + k0);
      f32x4 w1 = *(const f32x4*)(W + (size_t)col * NN + k0 + 4);
      f32x4 s0 = *(const f32x4*)(ds + k0);
      f32x4 s1 = *(const f32x4*)(ds + k0 + 4);
      short8 f;
      f[0]=(short)f2bf(w0[0]*s0[0]); f[1]=(short)f2bf(w0[1]*s0[1]);
      f[2]=(short)f2bf(w0[2]*s0[2]); f[3]=(short)f2bf(w0[3]*s0[3]);
      f[4]=(short)f2bf(w1[0]*s1[0]); f[5]=(short)f2bf(w1[1]*s1[1]);
      f[6]=(short)f2bf(w1[2]*s1[2]); f[7]=(short)f2bf(w1[3]*s1[3]);
      wf[c][j] = f;
    }
  }
  short8 bin;
#pragma unroll
  for (int e = 0; e < 8; ++e) {
    const int m = lg * 8 + e;
    bin[e] = (short)f2bf(m < NIN ? Bm[(size_t)i * NIN + m] : 0.0f);
  }
  const float itau = 1.0f / tau[i];

  unsigned* gt0 = obs32 + g * TILE32;              // parity-0 tile
  unsigned* gt1 = obs32 + PARSTRIDE + g * TILE32;  // parity-1 tile

  // ---- init r (C/D: row=lg*4+q, col=lr); publish tag 1 into parity 0 ----
  f32x4 r;
#pragma unroll
  for (int q = 0; q < 4; ++q) {
    const int row = lg * 4 + q;
    r[q] = r0[(size_t)(b0 + row) * NN + i];
    __hip_atomic_store(&gt0[row * NN + i],
                       (unsigned)f2bf(fmaxf(r[q], 0.f)) | (1u << 16),
                       __ATOMIC_RELAXED, SCOPE_AGENT);
  }

  const float* ub = u + (size_t)(b0 + lr) * NT * NIN;
  f32x4 up0 = {0,0,0,0}, up1 = {0,0,0,0};
  if (lg < 3) {
    up0 = *(const f32x4*)(ub + lg * 8);
    up1 = *(const f32x4*)(ub + lg * 8 + 4);
  }

  // time base: blocks leave the t=0 validated load within ~1 chain of each
  // other (it free-runs with retries); P's margin absorbs that skew.
  const unsigned long long T0 = __builtin_amdgcn_s_memrealtime();

  for (int t = 0; t < NT; ++t) {
    const unsigned tag  = (unsigned)(t + 1);
    const unsigned tag2 = (unsigned)(t + 2);
    unsigned* rdt = (t & 1) ? gt1 : gt0;
    unsigned* wrt = (t & 1) ? gt0 : gt1;

    // ---- pace: by T0 + t*P every block has published tag t+1 ----
    if (t) {
      const unsigned long long gate = T0 + (unsigned long long)t * P_ticks;
      for (;;) {
        if (__builtin_amdgcn_s_memrealtime() >= gate) break;
        __builtin_amdgcn_s_sleep(2);
      }
    }

    // ---- validated A load: rows=lr, k in this wave's slice (8 KB/wave) ----
    short8 af0, af1, af2, af3;
    {
      const unsigned* gp = rdt + lr * NN + wave * 128 + lg * 8;
      uint4v R0,R1,R2,R3,R4,R5,R6,R7;
      int guard = 0;
      for (;;) {
        asm volatile(
            "global_load_dwordx4 %0, %8, off sc0 sc1\n\t"
            "global_load_dwordx4 %1, %8, off offset:16 sc0 sc1\n\t"
            "global_load_dwordx4 %2, %8, off offset:128 sc0 sc1\n\t"
            "global_load_dwordx4 %3, %8, off offset:144 sc0 sc1\n\t"
            "global_load_dwordx4 %4, %8, off offset:256 sc0 sc1\n\t"
            "global_load_dwordx4 %5, %8, off offset:272 sc0 sc1\n\t"
            "global_load_dwordx4 %6, %8, off offset:384 sc0 sc1\n\t"
            "global_load_dwordx4 %7, %8, off offset:400 sc0 sc1\n\t"
            "s_waitcnt vmcnt(0)"
            : "=&v"(R0), "=&v"(R1), "=&v"(R2), "=&v"(R3),
              "=&v"(R4), "=&v"(R5), "=&v"(R6), "=&v"(R7)
            : "v"(gp) : "memory");
        unsigned bad = 0;
#define CK(Rx) bad |= ((Rx[0]>>16)^tag) | ((Rx[1]>>16)^tag) | \
                      ((Rx[2]>>16)^tag) | ((Rx[3]>>16)^tag)
        CK(R0); CK(R1); CK(R2); CK(R3); CK(R4); CK(R5); CK(R6); CK(R7);
#undef CK
        if (__all((int)(bad == 0))) break;
        if (++guard > RETRY_CAP) break;   // fail loud, never hang
      }
      PACKS8(af0, R0, R1); PACKS8(af1, R2, R3);
      PACKS8(af2, R4, R5); PACKS8(af3, R6, R7);
    }

    // ---- partial GEMM: 8 col-sets x 4 k-blocks (32 MFMA, static indices) ----
#pragma unroll
    for (int c = 0; c < 8; ++c) {
      f32x4 p = {0,0,0,0};
      p = MF(af0, wf[c][0], p);
      p = MF(af1, wf[c][1], p);
      p = MF(af2, wf[c][2], p);
      p = MF(af3, wf[c][3], p);
      pl[c * 8 + wave][lane] = p;
    }
    __syncthreads();

    f32x4 acc = pl[wave * 8 + 0][lane];
#pragma unroll
    for (int s = 1; s < 8; ++s)
      acc += pl[wave * 8 + s][lane];

    // ---- u-term folded in as one accumulate-MFMA (col-set = wave) ----
    short8 ua;
    ua[0]=(short)f2bf(up0[0]); ua[1]=(short)f2bf(up0[1]);
    ua[2]=(short)f2bf(up0[2]); ua[3]=(short)f2bf(up0[3]);
    ua[4]=(short)f2bf(up1[0]); ua[5]=(short)f2bf(up1[1]);
    ua[6]=(short)f2bf(up1[2]); ua[7]=(short)f2bf(up1[3]);
    if (lg >= 3) ua = short8{0,0,0,0,0,0,0,0};
    acc = MF(ua, bin, acc);

    // ---- state update (act = 60*sigmoid(0.28x-8.4) via native exp2) ----
    f32x4 rv;
#pragma unroll
    for (int q = 0; q < 4; ++q) {
      const float act = 60.0f / (1.0f + exp2f(12.118664f - 0.40395462f * acc[q]));
      rv[q] = r[q] + (0.1f * (act - r[q])) * itau;
      r[q]  = rv[q];
    }

    if (t != NT - 1) {
      // publish tagged obs (fire-and-forget agent stores)
#pragma unroll
      for (int q = 0; q < 4; ++q)
        __hip_atomic_store(&wrt[(lg * 4 + q) * NN + i],
                           (unsigned)f2bf(fmaxf(rv[q], 0.f)) | (tag2 << 16),
                           __ATOMIC_RELAXED, SCOPE_AGENT);
      // u prefetch for t+1
      if (lg < 3) {
        const float* up = ub + (t + 1) * NIN + lg * 8;
        up0 = *(const f32x4*)(up);
        up1 = *(const f32x4*)(up + 4);
      }
    }
#pragma unroll
    for (int q = 0; q < 4; ++q)
      out[((size_t)(b0 + lg * 4 + q) * NT + t) * NN + i] = rv[q];

    __syncthreads();   // LDS tiles reusable next step
  }

  // r_final
  const size_t fbase = (size_t)NBATCH * NT * NN;
#pragma unroll
  for (int q = 0; q < 4; ++q)
    out[fbase + (size_t)(b0 + lg * 4 + q) * NN + i] = r[q];
}

extern "C" void kernel_launch(void* const* d_in, const int* in_sizes, int n_in,
                              void* d_out, int out_size, void* d_ws, size_t ws_size,
                              hipStream_t stream) {
  const float* u   = (const float*)d_in[0];
  const float* r0  = (const float*)d_in[1];
  const float* W   = (const float*)d_in[2];
  const float* Bm  = (const float*)d_in[3];
  const float* tau = (const float*)d_in[4];
  const float* ds  = (const float*)d_in[5];
  float* out = (float*)d_out;

  unsigned* obs32 = (unsigned*)d_ws;

  // wall-clock rate (kHz) -> ticks per 2.1 us period; fallback 100 MHz RTC
  int wckhz = 0;
  if (hipDeviceGetAttribute(&wckhz, hipDeviceAttributeWallClockRate, 0)
          != hipSuccess || wckhz <= 0)
    wckhz = 100000;
  unsigned long long P_ticks =
      (unsigned long long)((2.1e-6) * (double)wckhz * 1000.0 + 0.5);
  if (P_ticks < 2) P_ticks = 2;

  // zero both epoch-tagged buffers every call (tags restart at 1 -> deterministic)
  hipMemsetAsync(d_ws, 0, 2 * PARSTRIDE * sizeof(unsigned), stream);

  rnn_step_all<<<dim3(32), dim3(512), 0, stream>>>(u, r0, W, Bm, tau, ds,
                                                   out, obs32, P_ticks);
}